// Round 3
// baseline (635.596 us; speedup 1.0000x reference)
//
#include <hip/hip_runtime.h>
#include <hip/hip_bf16.h>
#include <cstdint>
#include <cstddef>

typedef unsigned short u16;
typedef unsigned int u32;
typedef __attribute__((ext_vector_type(8))) short bf16x8;   // 8 bf16 = 4 VGPR
typedef __attribute__((ext_vector_type(4))) float f32x4;

#define ND 2048
#define BD 16384

// c_k = exp(-0.1) * 0.1^k / k!
#define C0 0.9048374180359595f
#define C1 0.09048374180359595f
#define C2 0.004524187090179798f
#define C3 1.5080623633932658e-4f
#define C4 3.770155908483165e-6f

__device__ __forceinline__ u16 f2bf(float f) {
  union { float f; u32 u; } v; v.f = f;
  u32 x = v.u;
  return (u16)((x + 0x7fffu + ((x >> 16) & 1u)) >> 16);   // RNE
}

__device__ __forceinline__ float bf2f(u16 b) {
  union { u32 u; float f; } v; v.u = ((u32)b) << 16; return v.f;
}

__device__ __forceinline__ void cp16(const void* g, void* l) {
  __builtin_amdgcn_global_load_lds(
      (const __attribute__((address_space(1))) u32*)g,
      (__attribute__((address_space(3))) u32*)l, 16, 0, 0);
}

// ---------------------------------------------------------------------------
// x (fp32) -> bf16, vectorized: 8 elems/thread
// ---------------------------------------------------------------------------
__global__ void cvt_x(const float* __restrict__ in, u16* __restrict__ out) {
  const size_t i = ((size_t)blockIdx.x * 256 + threadIdx.x) * 8;
  float4 a = ((const float4*)(in + i))[0];
  float4 b = ((const float4*)(in + i))[1];
  union { u16 u[8]; uint4 v; } o;
  o.u[0] = f2bf(a.x); o.u[1] = f2bf(a.y); o.u[2] = f2bf(a.z); o.u[3] = f2bf(a.w);
  o.u[4] = f2bf(b.x); o.u[5] = f2bf(b.y); o.u[6] = f2bf(b.z); o.u[7] = f2bf(b.w);
  *((uint4*)(out + i)) = o.v;
}

// ---------------------------------------------------------------------------
// Row softmax over off-diagonal (== softmax + zero diag + renorm) -> Abf
// ---------------------------------------------------------------------------
__global__ void row_softmax(const float* __restrict__ Theta, u16* __restrict__ Abf) {
  const int row = blockIdx.x;
  const int t = threadIdx.x;
  const float* tr = Theta + (size_t)row * ND;
  const int j0 = t * 8;
  float4 v0 = ((const float4*)tr)[t * 2];
  float4 v1 = ((const float4*)tr)[t * 2 + 1];
  float vals[8] = {v0.x, v0.y, v0.z, v0.w, v1.x, v1.y, v1.z, v1.w};

  float mx = -1e30f;
#pragma unroll
  for (int j = 0; j < 8; ++j)
    if (j0 + j != row) mx = fmaxf(mx, vals[j]);
#pragma unroll
  for (int o = 32; o > 0; o >>= 1) mx = fmaxf(mx, __shfl_xor(mx, o, 64));

  __shared__ float redm[4], reds[4];
  const int wv = t >> 6, ln = t & 63;
  if (ln == 0) redm[wv] = mx;
  __syncthreads();
  mx = fmaxf(fmaxf(redm[0], redm[1]), fmaxf(redm[2], redm[3]));

  float e[8];
  float s = 0.f;
#pragma unroll
  for (int j = 0; j < 8; ++j) {
    e[j] = (j0 + j == row) ? 0.f : expf(vals[j] - mx);
    s += e[j];
  }
#pragma unroll
  for (int o = 32; o > 0; o >>= 1) s += __shfl_xor(s, o, 64);
  if (ln == 0) reds[wv] = s;
  __syncthreads();
  s = reds[0] + reds[1] + reds[2] + reds[3];
  const float inv = 1.0f / s;

  union { u16 u[8]; uint4 v; } ab;
#pragma unroll
  for (int j = 0; j < 8; ++j) ab.u[j] = f2bf(e[j] * inv);
  *((uint4*)(Abf + (size_t)row * ND + j0)) = ab.v;
}

// ---------------------------------------------------------------------------
// bf16 transpose, 64x64 tiles
// ---------------------------------------------------------------------------
__global__ void transpose_bf16(const u16* __restrict__ in, u16* __restrict__ out) {
  __shared__ u16 tile[64][65];
  const int bx = blockIdx.x & 31, by = blockIdx.x >> 5;
  const int x = threadIdx.x & 63, y0 = threadIdx.x >> 6;
#pragma unroll
  for (int yy = y0; yy < 64; yy += 4)
    tile[yy][x] = in[(size_t)(by * 64 + yy) * ND + bx * 64 + x];
  __syncthreads();
#pragma unroll
  for (int yy = y0; yy < 64; yy += 4)
    out[(size_t)(bx * 64 + yy) * ND + by * 64 + x] = tile[x][yy];
}

// ---------------------------------------------------------------------------
// Deep-pipelined NT GEMM: C[M,N] = Ag[M,K] * Bg[N,K]^T, bf16 MFMA 16x16x32.
// 3 LDS buffers, issue distance 2, counted vmcnt (no drain-to-0 in loop),
// raw s_barrier, column-chunk-major LDS layout (conflict-free ds_read_b128
// with linear global_load_lds dest; the permutation lives in the global src).
// MODE 3: Bo[idx]=bf16(v); Bo2[idx]=bf16(c2*diag + c3*A + c4*v)   (A^2 + T)
// MODE 1: Bo[idx]=bf16(C1*A[idx] + v)                             (R final)
// MODE 2: Fo[idx]=C0*Xf[idx] + v                                  (output)
// ---------------------------------------------------------------------------
template <int BM, int BN, int WM, int WN, int THREADS, int MODE>
__global__ __launch_bounds__(THREADS, 2) void gemm_deep(
    const u16* __restrict__ Ag, const u16* __restrict__ Bg,
    float* __restrict__ Fo, u16* __restrict__ Bo, u16* __restrict__ Bo2,
    const u16* __restrict__ Aux, const float* __restrict__ Xf,
    int Nn, int K, int gridn) {
  constexpr int LOGM = (BM == 256) ? 8 : 7;
  constexpr int LOGN = (BN == 256) ? 8 : 7;
  constexpr int FM = BM / WM / 16;
  constexpr int FN = BN / WN / 16;
  constexpr int CHA = BM * 4 / THREADS;   // 16B chunks per thread (A tile)
  constexpr int CHB = BN * 4 / THREADS;

  __shared__ u16 lA[3][BM * 32];
  __shared__ u16 lB[3][BN * 32];

  const int tid = threadIdx.x;
  const int lane = tid & 63;
  const int wave = tid >> 6;
  const int wm = wave / WN;
  const int wn = wave % WN;
  const int lr = lane & 15;
  const int kc = lane >> 4;               // which 8-elem k-chunk of BK=32

  // bijective XCD swizzle (all grids are multiples of 8)
  const int nwg = gridDim.x;
  const int bid = blockIdx.x;
  const int swz = (bid & 7) * (nwg >> 3) + (bid >> 3);
  const int bm = swz / gridn;
  const int bn = swz % gridn;

  const u16* Abase = Ag + (size_t)bm * BM * K;
  const u16* Bbase = Bg + (size_t)bn * BN * K;

  f32x4 acc[FM][FN];
#pragma unroll
  for (int i = 0; i < FM; ++i)
#pragma unroll
    for (int j = 0; j < FN; ++j)
      acc[i][j] = (f32x4){0.f, 0.f, 0.f, 0.f};

  // LDS layout: 16B chunk index ell = kchunk*B? + row  (column-chunk-major).
  // gload_lds dest stays linear in tid; global src carries the permutation.
  auto stage = [&](int s, int kt) {
    const int kbase = kt * 32;
#pragma unroll
    for (int q = 0; q < CHA; ++q) {
      int c = q * THREADS + tid;
      int kcc = c >> LOGM, row = c & (BM - 1);
      cp16(Abase + (size_t)row * K + kbase + kcc * 8, &lA[s][c * 8]);
    }
#pragma unroll
    for (int q = 0; q < CHB; ++q) {
      int c = q * THREADS + tid;
      int kcc = c >> LOGN, col = c & (BN - 1);
      cp16(Bbase + (size_t)col * K + kbase + kcc * 8, &lB[s][c * 8]);
    }
  };

  auto compute = [&](int s) {
    bf16x8 af[FM], bg[FN];
#pragma unroll
    for (int m = 0; m < FM; ++m) {
      int row = wm * (BM / WM) + m * 16 + lr;
      af[m] = *(const bf16x8*)&lA[s][(kc * BM + row) * 8];
    }
#pragma unroll
    for (int n = 0; n < FN; ++n) {
      int col = wn * (BN / WN) + n * 16 + lr;
      bg[n] = *(const bf16x8*)&lB[s][(kc * BN + col) * 8];
    }
    __builtin_amdgcn_s_setprio(1);
#pragma unroll
    for (int m = 0; m < FM; ++m)
#pragma unroll
      for (int n = 0; n < FN; ++n)
        acc[m][n] = __builtin_amdgcn_mfma_f32_16x16x32_bf16(af[m], bg[n], acc[m][n], 0, 0, 0);
    __builtin_amdgcn_s_setprio(0);
  };

  const int NT = K >> 5;                  // 64 for K=2048
  stage(0, 0);
  stage(1, 1);
  for (int t = 0; t < NT - 2; ++t) {
    stage((t + 2) % 3, t + 2);
    // tiles t+1, t+2 may stay in flight (8 loads); tile t guaranteed landed
    asm volatile("s_waitcnt vmcnt(8)" ::: "memory");
    __builtin_amdgcn_s_barrier();
    compute(t % 3);
    __builtin_amdgcn_s_barrier();        // reads done before slot reuse
  }
  asm volatile("s_waitcnt vmcnt(4)" ::: "memory");
  __builtin_amdgcn_s_barrier();
  compute((NT - 2) % 3);
  __builtin_amdgcn_s_barrier();
  asm volatile("s_waitcnt vmcnt(0)" ::: "memory");
  __builtin_amdgcn_s_barrier();
  compute((NT - 1) % 3);

  // epilogue: C/D layout col=lane&15, row=(lane>>4)*4+reg (m89-verified)
  const int r0 = (lane >> 4) << 2;
#pragma unroll
  for (int m = 0; m < FM; ++m) {
    const int grow0 = bm * BM + wm * (BM / WM) + m * 16 + r0;
#pragma unroll
    for (int n = 0; n < FN; ++n) {
      const int gcol = bn * BN + wn * (BN / WN) + n * 16 + lr;
#pragma unroll
      for (int r = 0; r < 4; ++r) {
        const int grow = grow0 + r;
        const size_t idx = (size_t)grow * Nn + gcol;
        const float v = acc[m][n][r];
        if (MODE == 3) {
          Bo[idx] = f2bf(v);                                   // A^2
          float tv = ((grow == gcol) ? C2 : 0.0f) + C3 * bf2f(Aux[idx]) + C4 * v;
          Bo2[idx] = f2bf(tv);                                 // T
        } else if (MODE == 1) {
          Bo[idx] = f2bf(C1 * bf2f(Aux[idx]) + v);             // R
        } else {
          Fo[idx] = C0 * Xf[idx] + v;                          // out
        }
      }
    }
  }
}

// ---------------------------------------------------------------------------
extern "C" void kernel_launch(void* const* d_in, const int* in_sizes, int n_in,
                              void* d_out, int out_size, void* d_ws, size_t ws_size,
                              hipStream_t stream) {
  const float* x = (const float*)d_in[0];       // [16384, 2048] fp32
  const float* Theta = (const float*)d_in[1];   // [2048, 2048] fp32
  float* out = (float*)d_out;                   // [16384, 2048] fp32

  char* ws = (char*)d_ws;
  u16* xbf  = (u16*)(ws);                       // 67108864 B
  u16* Abf  = (u16*)(ws + 67108864);            //  8388608 B
  u16* Atbf = (u16*)(ws + 75497472);            //  8388608 B
  u16* P2   = (u16*)(ws + 83886080);            //  8388608 B
  u16* Tbf  = (u16*)(ws + 92274688);            //  8388608 B
  u16* Ttbf = (u16*)(ws + 100663296);           //  8388608 B
  u16* Rbf  = (u16*)(ws + 109051904);           //  8388608 B  (total 112 MiB)

  // x -> bf16
  cvt_x<<<dim3(16384), dim3(256), 0, stream>>>(x, xbf);
  // A = offdiag-softmax(Theta)
  row_softmax<<<dim3(2048), dim3(256), 0, stream>>>(Theta, Abf);
  // At = A^T
  transpose_bf16<<<dim3(1024), dim3(256), 0, stream>>>(Abf, Atbf);
  // GEMM1: P2 = A*A ; T = c2*I + c3*A + c4*A^2
  gemm_deep<128, 128, 2, 2, 256, 3><<<dim3(256), dim3(256), 0, stream>>>(
      Abf, Atbf, nullptr, P2, Tbf, Abf, nullptr, ND, ND, 16);
  // Tt = T^T
  transpose_bf16<<<dim3(1024), dim3(256), 0, stream>>>(Tbf, Ttbf);
  // GEMM2: Q = A^2 * T ; Rbf = bf16(c1*A + Q)   (R = c1A+c2A^2+c3A^3+c4A^4)
  gemm_deep<128, 128, 2, 2, 256, 1><<<dim3(256), dim3(256), 0, stream>>>(
      P2, Ttbf, nullptr, Rbf, nullptr, Abf, nullptr, ND, ND, 16);
  // BIG: out = c0*x + xbf @ Rbf^T
  gemm_deep<256, 256, 2, 4, 512, 2><<<dim3(512), dim3(512), 0, stream>>>(
      xbf, Rbf, out, nullptr, nullptr, nullptr, x, ND, ND, 8);
}

// Round 9
// 586.618 us; speedup vs baseline: 1.0835x; 1.0835x over previous
//
#include <hip/hip_runtime.h>
#include <hip/hip_bf16.h>
#include <cstdint>
#include <cstddef>

typedef unsigned short u16;
typedef unsigned int u32;
typedef __attribute__((ext_vector_type(8))) short bf16x8;   // 8 bf16 = 4 VGPR
typedef __attribute__((ext_vector_type(4))) float f32x4;

#define ND 2048
#define BD 16384

// c_k = exp(-0.1) * 0.1^k / k!
#define C0 0.9048374180359595f
#define C1 0.09048374180359595f
#define C2 0.004524187090179798f
#define C3 1.5080623633932658e-4f
#define C4 3.770155908483165e-6f

__device__ __forceinline__ u16 f2bf(float f) {
  union { float f; u32 u; } v; v.f = f;
  u32 x = v.u;
  return (u16)((x + 0x7fffu + ((x >> 16) & 1u)) >> 16);   // RNE
}

__device__ __forceinline__ float bf2f(u16 b) {
  union { u32 u; float f; } v; v.u = ((u32)b) << 16; return v.f;
}

__device__ __forceinline__ void cp16(const void* g, void* l) {
  __builtin_amdgcn_global_load_lds(
      (const __attribute__((address_space(1))) u32*)g,
      (__attribute__((address_space(3))) u32*)l, 16, 0, 0);
}

// ---------------------------------------------------------------------------
// x (fp32) -> bf16, vectorized: 8 elems/thread
// ---------------------------------------------------------------------------
__global__ void cvt_x(const float* __restrict__ in, u16* __restrict__ out) {
  const size_t i = ((size_t)blockIdx.x * 256 + threadIdx.x) * 8;
  float4 a = ((const float4*)(in + i))[0];
  float4 b = ((const float4*)(in + i))[1];
  union { u16 u[8]; uint4 v; } o;
  o.u[0] = f2bf(a.x); o.u[1] = f2bf(a.y); o.u[2] = f2bf(a.z); o.u[3] = f2bf(a.w);
  o.u[4] = f2bf(b.x); o.u[5] = f2bf(b.y); o.u[6] = f2bf(b.z); o.u[7] = f2bf(b.w);
  *((uint4*)(out + i)) = o.v;
}

// ---------------------------------------------------------------------------
// Row softmax over off-diagonal (== softmax + zero diag + renorm) -> Abf
// ---------------------------------------------------------------------------
__global__ void row_softmax(const float* __restrict__ Theta, u16* __restrict__ Abf) {
  const int row = blockIdx.x;
  const int t = threadIdx.x;
  const float* tr = Theta + (size_t)row * ND;
  const int j0 = t * 8;
  float4 v0 = ((const float4*)tr)[t * 2];
  float4 v1 = ((const float4*)tr)[t * 2 + 1];
  float vals[8] = {v0.x, v0.y, v0.z, v0.w, v1.x, v1.y, v1.z, v1.w};

  float mx = -1e30f;
#pragma unroll
  for (int j = 0; j < 8; ++j)
    if (j0 + j != row) mx = fmaxf(mx, vals[j]);
#pragma unroll
  for (int o = 32; o > 0; o >>= 1) mx = fmaxf(mx, __shfl_xor(mx, o, 64));

  __shared__ float redm[4], reds[4];
  const int wv = t >> 6, ln = t & 63;
  if (ln == 0) redm[wv] = mx;
  __syncthreads();
  mx = fmaxf(fmaxf(redm[0], redm[1]), fmaxf(redm[2], redm[3]));

  float e[8];
  float s = 0.f;
#pragma unroll
  for (int j = 0; j < 8; ++j) {
    e[j] = (j0 + j == row) ? 0.f : expf(vals[j] - mx);
    s += e[j];
  }
#pragma unroll
  for (int o = 32; o > 0; o >>= 1) s += __shfl_xor(s, o, 64);
  if (ln == 0) reds[wv] = s;
  __syncthreads();
  s = reds[0] + reds[1] + reds[2] + reds[3];
  const float inv = 1.0f / s;

  union { u16 u[8]; uint4 v; } ab;
#pragma unroll
  for (int j = 0; j < 8; ++j) ab.u[j] = f2bf(e[j] * inv);
  *((uint4*)(Abf + (size_t)row * ND + j0)) = ab.v;
}

// ---------------------------------------------------------------------------
// bf16 transpose, 64x64 tiles (2048x2048 only)
// ---------------------------------------------------------------------------
__global__ void transpose_bf16(const u16* __restrict__ in, u16* __restrict__ out) {
  __shared__ u16 tile[64][65];
  const int bx = blockIdx.x & 31, by = blockIdx.x >> 5;
  const int x = threadIdx.x & 63, y0 = threadIdx.x >> 6;
#pragma unroll
  for (int yy = y0; yy < 64; yy += 4)
    tile[yy][x] = in[(size_t)(by * 64 + yy) * ND + bx * 64 + x];
  __syncthreads();
#pragma unroll
  for (int yy = y0; yy < 64; yy += 4)
    out[(size_t)(bx * 64 + yy) * ND + by * 64 + x] = tile[x][yy];
}

// ---------------------------------------------------------------------------
// Phased NT GEMM: C[M,N] = Ag[M,K] * Bg[N,K]^T, bf16 MFMA 16x16x32, BK=64.
// 4 quadrant-phases per K-tile (mh,nh); waves own SPLIT rows/cols so every
// phase consumes one shared A-half/B-half. Half-tile staging into the dead
// dbuf, counted vmcnt(4) placed immediately before a barrier, dependent
// ds_reads strictly after that barrier (chip-wide landing guaranteed; loads
// aged 4 phases; never drain to 0 mid-loop). Column-chunk-major LDS layout
// (conflict-free reads, linear gload_lds dest). T5 setprio around MFMA.
// MODE 3: Bo=bf16(v); Bo2=bf16(c2*diag + c3*Aux + c4*v)     (A^2 and T)
// MODE 1: Bo=bf16(C1*Aux + v)                               (R final)
// MODE 2: Fo=C0*Xf + v                                      (big output)
// ---------------------------------------------------------------------------
template <int BM, int BN, int WM, int WN, int THREADS, int MODE>
__global__ __launch_bounds__(THREADS, 2) void gemm8(
    const u16* __restrict__ Ag, const u16* __restrict__ Bg,
    float* __restrict__ Fo, u16* __restrict__ Bo, u16* __restrict__ Bo2,
    const u16* __restrict__ Aux, const float* __restrict__ Xf,
    int Nn, int K, int gridm) {
  constexpr int BK = 64;
  constexpr int HM = BM / 2, HN = BN / 2;     // half sizes
  constexpr int RH = HM / WM, CH = HN / WN;   // per-wave rows/cols per half
  constexpr int FMH = RH / 16, FNH = CH / 16; // frags per half
  constexpr int LA = HM * 8 / THREADS;        // 16B loads/thread per A-half
  constexpr int LB = HN * 8 / THREADS;
  static_assert(LA == 2 && LB == 2, "vmcnt(4) math assumes 2+2 loads per half-pair");
  static_assert(FMH >= 1 && FNH >= 1, "bad wave geometry");

  __shared__ u16 lA[2][2][HM * BK];           // [buf][half][chunks]
  __shared__ u16 lB[2][2][HN * BK];

  const int tid = threadIdx.x;
  const int lane = tid & 63;
  const int wave = tid >> 6;
  const int wm = wave / WN, wn = wave % WN;
  const int lr = lane & 15, khi = lane >> 4;

  // bijective XCD swizzle (all grids % 8 == 0)
  const int nwg = gridDim.x, bid = blockIdx.x;
  const int swz = (bid & 7) * (nwg >> 3) + (bid >> 3);
  const int bm = swz % gridm, bn = swz / gridm;

  const u16* Ab = Ag + (size_t)bm * BM * K;
  const u16* Bb = Bg + (size_t)bn * BN * K;

  f32x4 acc[2 * FMH][2 * FNH];
#pragma unroll
  for (int i = 0; i < 2 * FMH; ++i)
#pragma unroll
    for (int j = 0; j < 2 * FNH; ++j)
      acc[i][j] = (f32x4){0.f, 0.f, 0.f, 0.f};

  // stage one half-tile: chunk c = kc*H + row (column-chunk-major); LDS dest
  // linear in tid (wave-uniform base + lane*16 -- rule 21 safe), permutation
  // carried by the per-lane global source address.
  auto stA = [&](int b, int h, int kt) {
#pragma unroll
    for (int q = 0; q < LA; ++q) {
      int c = q * THREADS + tid;
      int kc = c / HM, row = c % HM;
      cp16(Ab + (size_t)(h * HM + row) * K + kt * BK + kc * 8, &lA[b][h][c * 8]);
    }
  };
  auto stB = [&](int b, int h, int kt) {
#pragma unroll
    for (int q = 0; q < LB; ++q) {
      int c = q * THREADS + tid;
      int kc = c / HN, col = c % HN;
      cp16(Bb + (size_t)(h * HN + col) * K + kt * BK + kc * 8, &lB[b][h][c * 8]);
    }
  };

  bf16x8 af[FMH][2], bfr[FNH][2];
  auto rdA = [&](int b, int mh) {
#pragma unroll
    for (int fm = 0; fm < FMH; ++fm)
#pragma unroll
      for (int ks = 0; ks < 2; ++ks) {
        int row = wm * RH + fm * 16 + lr;
        int kc = ks * 4 + khi;
        af[fm][ks] = *(const bf16x8*)&lA[b][mh][(kc * HM + row) * 8];
      }
  };
  auto rdB = [&](int b, int nh) {
#pragma unroll
    for (int fn = 0; fn < FNH; ++fn)
#pragma unroll
      for (int ks = 0; ks < 2; ++ks) {
        int col = wn * CH + fn * 16 + lr;
        int kc = ks * 4 + khi;
        bfr[fn][ks] = *(const bf16x8*)&lB[b][nh][(kc * HN + col) * 8];
      }
  };
  auto mm = [&](int mh, int nh) {
    __builtin_amdgcn_s_setprio(1);
#pragma unroll
    for (int ks = 0; ks < 2; ++ks)
#pragma unroll
      for (int fm = 0; fm < FMH; ++fm)
#pragma unroll
        for (int fn = 0; fn < FNH; ++fn)
          acc[mh * FMH + fm][nh * FNH + fn] = __builtin_amdgcn_mfma_f32_16x16x32_bf16(
              af[fm][ks], bfr[fn][ks], acc[mh * FMH + fm][nh * FNH + fn], 0, 0, 0);
    __builtin_amdgcn_s_setprio(0);
  };

  const int NT = K / BK;  // 32
  // prologue: tile 0, issue order [Ah0, Bh0, Bh1, Ah1] (matches wait logic)
  stA(0, 0, 0); stB(0, 0, 0); stB(0, 1, 0); stA(0, 1, 0);
  asm volatile("s_waitcnt vmcnt(4)" ::: "memory");   // Ah0,Bh0 of tile 0 landed
  __builtin_amdgcn_s_barrier();

  for (int t = 0; t < NT; ++t) {
    const int b = t & 1, nb = b ^ 1;
    const bool pre = (t + 1 < NT);
    // P0 (mh0,nh0): reads verified by the wait+barrier that ended prev tile
    rdA(b, 0); rdB(b, 0);
    if (pre) { stA(nb, 0, t + 1); stB(nb, 0, t + 1); }
    mm(0, 0);
    if (pre) asm volatile("s_waitcnt vmcnt(4)" ::: "memory");  // t's Bh1,Ah1 landed
    else     asm volatile("s_waitcnt vmcnt(0)" ::: "memory");
    __builtin_amdgcn_s_barrier();
    // P1 (mh0,nh1)
    rdB(b, 1);
    if (pre) { stB(nb, 1, t + 1); stA(nb, 1, t + 1); }
    mm(0, 1);
    __builtin_amdgcn_s_barrier();
    // P2 (mh1,nh1)
    rdA(b, 1);
    mm(1, 1);
    __builtin_amdgcn_s_barrier();
    // P3 (mh1,nh0)
    rdB(b, 0);
    mm(1, 0);
    if (pre) asm volatile("s_waitcnt vmcnt(4)" ::: "memory");  // t+1's Ah0,Bh0 landed
    __builtin_amdgcn_s_barrier();
  }

  // epilogue: C/D layout col=lane&15, row=(lane>>4)*4+reg (m89-verified)
#pragma unroll
  for (int mh = 0; mh < 2; ++mh)
#pragma unroll
    for (int fm = 0; fm < FMH; ++fm) {
      const int grow0 = bm * BM + mh * HM + wm * RH + fm * 16 + (khi << 2);
#pragma unroll
      for (int nh = 0; nh < 2; ++nh)
#pragma unroll
        for (int fn = 0; fn < FNH; ++fn) {
          const int gcol = bn * BN + nh * HN + wn * CH + fn * 16 + lr;
#pragma unroll
          for (int r = 0; r < 4; ++r) {
            const int grow = grow0 + r;
            const size_t idx = (size_t)grow * Nn + gcol;
            const float v = acc[mh * FMH + fm][nh * FNH + fn][r];
            if (MODE == 3) {
              Bo[idx] = f2bf(v);                                   // A^2
              float tv = ((grow == gcol) ? C2 : 0.0f) + C3 * bf2f(Aux[idx]) + C4 * v;
              Bo2[idx] = f2bf(tv);                                 // T
            } else if (MODE == 1) {
              Bo[idx] = f2bf(C1 * bf2f(Aux[idx]) + v);             // R
            } else {
              Fo[idx] = C0 * Xf[idx] + v;                          // out
            }
          }
        }
    }
}

// ---------------------------------------------------------------------------
extern "C" void kernel_launch(void* const* d_in, const int* in_sizes, int n_in,
                              void* d_out, int out_size, void* d_ws, size_t ws_size,
                              hipStream_t stream) {
  const float* x = (const float*)d_in[0];       // [16384, 2048] fp32
  const float* Theta = (const float*)d_in[1];   // [2048, 2048] fp32
  float* out = (float*)d_out;                   // [16384, 2048] fp32

  char* ws = (char*)d_ws;
  u16* xbf  = (u16*)(ws);                       // 67108864 B
  u16* Abf  = (u16*)(ws + 67108864);            //  8388608 B
  u16* Atbf = (u16*)(ws + 75497472);            //  8388608 B
  u16* P2   = (u16*)(ws + 83886080);            //  8388608 B
  u16* Tbf  = (u16*)(ws + 92274688);            //  8388608 B
  u16* Ttbf = (u16*)(ws + 100663296);           //  8388608 B
  u16* Rbf  = (u16*)(ws + 109051904);           //  8388608 B  (total 112 MiB)

  // x -> bf16
  cvt_x<<<dim3(16384), dim3(256), 0, stream>>>(x, xbf);
  // A = offdiag-softmax(Theta)
  row_softmax<<<dim3(2048), dim3(256), 0, stream>>>(Theta, Abf);
  // At = A^T
  transpose_bf16<<<dim3(1024), dim3(256), 0, stream>>>(Abf, Atbf);
  // G1: P2 = A*A ; T = c2*I + c3*A + c4*A^2   (64² tiles, 2-wave, 4 blk/CU)
  gemm8<64, 64, 1, 2, 128, 3><<<dim3(1024), dim3(128), 0, stream>>>(
      Abf, Atbf, nullptr, P2, Tbf, Abf, nullptr, ND, ND, 32);
  // Tt = T^T
  transpose_bf16<<<dim3(1024), dim3(256), 0, stream>>>(Tbf, Ttbf);
  // G2: Q = A^2 * T ; Rbf = bf16(c1*A + Q)
  gemm8<64, 64, 1, 2, 128, 1><<<dim3(1024), dim3(128), 0, stream>>>(
      P2, Ttbf, nullptr, Rbf, nullptr, Abf, nullptr, ND, ND, 32);
  // BIG: out = c0*x + xbf @ Rbf^T   (256² tile, 8 waves, bn-per-XCD swizzle)
  gemm8<256, 256, 2, 4, 512, 2><<<dim3(512), dim3(512), 0, stream>>>(
      xbf, Rbf, out, nullptr, nullptr, nullptr, x, ND, ND, 64);
}